// Round 7
// baseline (8519.932 us; speedup 1.0000x reference)
//
#include <hip/hip_runtime.h>
#include <hip/hip_bf16.h>
#include <math.h>

#define T_STEPS 512
#define BATCH   64
#define INDIM   1024
#define HDIM    1024
#define NWG     128      // persistent WGs; each owns 8 hidden cols
#define NCHAIN  4        // independent batch chains of 16 rows each

using bf16x8 = __attribute__((ext_vector_type(8))) __bf16;
using f32x4  = __attribute__((ext_vector_type(4))) float;
typedef unsigned long long u64;

struct WP {
    const float* wx[4];
    const float* wh[4];
    const float* bx[4];
    const float* bh[4];
};

// Pack 8 weight matrices into combined bf16 [4H][K] layouts + combined bias.
__global__ void pack_weights(WP p, __hip_bfloat16* __restrict__ Wx,
                             __hip_bfloat16* __restrict__ Wh, float* __restrict__ bias)
{
    int i = blockIdx.x * blockDim.x + threadIdx.x;
    const int stride = gridDim.x * blockDim.x;
    const int total = 4 * HDIM * INDIM;
    for (int idx = i; idx < total; idx += stride) {
        int g = idx >> 20;
        int r = idx & ((1 << 20) - 1);
        Wx[idx] = __float2bfloat16(p.wx[g][r]);
        Wh[idx] = __float2bfloat16(p.wh[g][r]);
    }
    if (i < 4 * HDIM) {
        int g = i >> 10, r = i & 1023;
        bias[i] = p.bx[g][r] + p.bh[g][r];
    }
}

__global__ void cast_f32_bf16(const float* __restrict__ in,
                              __hip_bfloat16* __restrict__ out, int n4)
{
    int i = blockIdx.x * blockDim.x + threadIdx.x;
    const int stride = gridDim.x * blockDim.x;
    for (; i < n4; i += stride) {
        float4 v = ((const float4*)in)[i];
        union { __hip_bfloat16 b[4]; short4 s; } u;
        u.b[0] = __float2bfloat16(v.x);
        u.b[1] = __float2bfloat16(v.y);
        u.b[2] = __float2bfloat16(v.z);
        u.b[3] = __float2bfloat16(v.w);
        ((short4*)out)[i] = u.s;
    }
}

// hbuf layout: [slot(2)][chain(4)][16][1024] bf16
__global__ void init_state(const float* __restrict__ H0, const float* __restrict__ C0,
                           __hip_bfloat16* __restrict__ hbuf, float* __restrict__ c)
{
    int i = blockIdx.x * blockDim.x + threadIdx.x;
    if (i < BATCH * HDIM) {
        int b = i >> 10, j = i & 1023;
        int chain = b >> 4, bl = b & 15;
        hbuf[((size_t)chain << 14) + (bl << 10) + j] = __float2bfloat16(H0[i]);
        c[i] = C0[i];
    }
}

__global__ void epilogue(const float* __restrict__ lasth, const float* __restrict__ c,
                         float* __restrict__ Hf, float* __restrict__ Cf)
{
    int i = blockIdx.x * blockDim.x + threadIdx.x;
    if (i < BATCH * HDIM) {
        Hf[i] = lasth[i];
        Cf[i] = c[i];
    }
}

// xproj GEMM: xp[t][n][b] = sum_k xb[t*64+b][k] * Wx[n][k]   (f32 out)
__global__ __launch_bounds__(256, 2) void xproj_gemm(
    const __hip_bfloat16* __restrict__ xb,   // chunk base [TC*64][1024]
    const __hip_bfloat16* __restrict__ Wx,   // [4096][1024]
    float* __restrict__ xp)                  // [TC][4096][64]
{
    __shared__ float ct[4][64][33];
    const int t = blockIdx.x;
    const int n0 = blockIdx.y << 7;
    const int tid = threadIdx.x, w = tid >> 6, lane = tid & 63;
    const int rA = lane & 15, kg = (lane >> 4) << 3;
    const int nw = n0 + (w << 5);
    f32x4 acc[2][4] = {};
    const __hip_bfloat16* Arow = xb + (((size_t)t << 6) + rA) * 1024 + kg;
    const __hip_bfloat16* Brow = Wx + ((size_t)(nw + rA) << 10) + kg;
#pragma unroll 4
    for (int kk = 0; kk < 32; ++kk) {
        const int kb = kk << 5;
        bf16x8 bf0 = *reinterpret_cast<const bf16x8*>(Brow + kb);
        bf16x8 bf1 = *reinterpret_cast<const bf16x8*>(Brow + (16 << 10) + kb);
        bf16x8 af[4];
#pragma unroll
        for (int m = 0; m < 4; ++m)
            af[m] = *reinterpret_cast<const bf16x8*>(Arow + (m << 14) + kb);
#pragma unroll
        for (int m = 0; m < 4; ++m) {
            acc[0][m] = __builtin_amdgcn_mfma_f32_16x16x32_bf16(af[m], bf0, acc[0][m], 0, 0, 0);
            acc[1][m] = __builtin_amdgcn_mfma_f32_16x16x32_bf16(af[m], bf1, acc[1][m], 0, 0, 0);
        }
    }
#pragma unroll
    for (int n2 = 0; n2 < 2; ++n2)
#pragma unroll
        for (int m = 0; m < 4; ++m) {
            const int bb = (m << 4) + ((lane >> 4) << 2);
#pragma unroll
            for (int r = 0; r < 4; ++r)
                ct[w][bb + r][(n2 << 4) + rA] = acc[n2][m][r];
        }
    __syncthreads();
    const int n = lane & 31, mh = lane >> 5;
    float* obase = xp + ((size_t)t * 4096 + nw + n) * 64 + (mh << 5);
#pragma unroll
    for (int j = 0; j < 8; ++j) {
        const int m0 = (mh << 5) + (j << 2);
        *reinterpret_cast<float4*>(obase + (j << 2)) = make_float4(
            ct[w][m0 + 0][n], ct[w][m0 + 1][n], ct[w][m0 + 2][n], ct[w][m0 + 3][n]);
    }
}

__device__ __forceinline__ float fast_sigmoid(float x)
{
    return 1.f / (1.f + __expf(-x));
}
__device__ __forceinline__ float fast_tanh(float x)
{
    x = fminf(15.f, fmaxf(-15.f, x));
    const float e = __expf(2.f * x);
    return (e - 1.f) / (e + 1.f);
}

// Persistent 4-chain recurrence. Grid = NWG(128) x 256 threads.
// WG owns 8 hidden cols; batch split into 4 chains of 16 rows. Per timestep,
// phases g=0..3 process chain g; each chain's store->flag->detect->load
// round-trip hides under the other 3 chains' phases. Flag for chain g is
// posted one phase later (after a __syncthreads that drains the h-store
// acks), so no dedicated ack-stall. All cross-WG data via relaxed
// agent-scope atomics (MALL-coherent, no L2 fences).
__global__ __launch_bounds__(256, 1) void lstm_persist(
    const float* __restrict__ xp,            // [TC][4096][64]
    const __hip_bfloat16* __restrict__ Wh,   // [4096][1024]
    const float* __restrict__ bias,          // [4096]
    __hip_bfloat16* __restrict__ hbuf,       // [2][4][16][1024]
    float* __restrict__ cbuf,                // [64][1024]
    float* __restrict__ out,                 // [TC][64][1024]
    unsigned* __restrict__ flags,            // [4][NWG*16]
    unsigned stepBase,
    int TC)
{
    __shared__ float gl[4][16][36];          // per-wave partials (pad 36: no conflicts)
    __shared__ float hs[16][9];              // gathered h f32

    const int tid  = threadIdx.x;
    const int w    = tid >> 6;
    const int lane = tid & 63;
    const int rA   = lane & 15;
    const int kg   = (lane >> 4) << 3;
    const int j0   = blockIdx.x << 3;

    // Wave's Wh fragments: its K-quarter of the WG's 32 gate-rows.
    // gate-row r -> global row (r>>3)*1024 + j0 + (r&7)
    bf16x8 whf[2][8];
#pragma unroll
    for (int n2 = 0; n2 < 2; ++n2) {
        const int row  = (n2 << 4) + rA;
        const int grow = ((row >> 3) << 10) + j0 + (row & 7);
        const __hip_bfloat16* wr = Wh + ((size_t)grow << 10) + (w << 8) + kg;
#pragma unroll
        for (int kk = 0; kk < 8; ++kk)
            whf[n2][kk] = *reinterpret_cast<const bf16x8*>(wr + (kk << 5));
    }

    // Gate-phase state: thread tid<128 owns (b_local=tid>>3, col=tid&7)
    const int gb = tid >> 3;
    const int gc = tid & 7;
    float creg[NCHAIN], brg[4];
    if (tid < 128) {
#pragma unroll
        for (int gt = 0; gt < 4; ++gt) brg[gt] = bias[(gt << 10) + j0 + gc];
#pragma unroll
        for (int g = 0; g < NCHAIN; ++g)
            creg[g] = cbuf[(((g << 4) + gb) << 10) + j0 + gc];
    }

    const int fstride = NWG * 16;

    for (int s = 0; s < TC; ++s) {
        const int slr = (int)((stepBase + (unsigned)s) & 1);
        const int slw = slr ^ 1;
        const unsigned tgt = stepBase + (unsigned)s;

#pragma unroll 1
        for (int g = 0; g < NCHAIN; ++g) {
            // xproj loads for this (chain, step): issue before the wait,
            // consumed in gates (latency hidden under poll+GEMM).
            float xv[4];
            if (tid < 128) {
                const float* xpt = xp + (size_t)s * 262144 + (g << 4) + gb;
#pragma unroll
                for (int gt = 0; gt < 4; ++gt)
                    xv[gt] = xpt[((gt << 10) + j0 + gc) << 6];
            }

            // Wait for chain g's h(s) from all WGs.
            if (tid < 64) {
                const unsigned* f0 = flags + g * fstride + tid * 16;
                const unsigned* f1 = f0 + 64 * 16;
                int guard = 1 << 20;
                while ((__hip_atomic_load(f0, __ATOMIC_RELAXED, __HIP_MEMORY_SCOPE_AGENT) < tgt ||
                        __hip_atomic_load(f1, __ATOMIC_RELAXED, __HIP_MEMORY_SCOPE_AGENT) < tgt)
                       && --guard > 0)
                    __builtin_amdgcn_s_sleep(1);
            }
            __syncthreads();   // also drains previous phase's h-store acks

            // Deferred flag post for chain (g-1): its stores are now drained.
            if (tid == 0) {
                const unsigned pv = tgt + (g == 0 ? 0u : 1u);
                __hip_atomic_store(flags + ((g + 3) & 3) * fstride + (int)blockIdx.x * 16,
                                   pv, __ATOMIC_RELAXED, __HIP_MEMORY_SCOPE_AGENT);
            }

            // h-GEMM for chain g: M=16 rows, this wave's K-quarter.
            const __hip_bfloat16* hb =
                hbuf + (((size_t)((slr << 2) + g)) << 14) + (rA << 10) + (w << 8) + kg;
            u64 aq[8][2];
#pragma unroll
            for (int kk = 0; kk < 8; ++kk) {
                const u64* p = (const u64*)(hb + (kk << 5));
                aq[kk][0] = __hip_atomic_load(p,     __ATOMIC_RELAXED, __HIP_MEMORY_SCOPE_AGENT);
                aq[kk][1] = __hip_atomic_load(p + 1, __ATOMIC_RELAXED, __HIP_MEMORY_SCOPE_AGENT);
            }
            f32x4 acc[2] = {};
#pragma unroll
            for (int kk = 0; kk < 8; ++kk) {
                union { u64 q[2]; bf16x8 v; } c;
                c.q[0] = aq[kk][0];
                c.q[1] = aq[kk][1];
                acc[0] = __builtin_amdgcn_mfma_f32_16x16x32_bf16(c.v, whf[0][kk], acc[0], 0, 0, 0);
                acc[1] = __builtin_amdgcn_mfma_f32_16x16x32_bf16(c.v, whf[1][kk], acc[1], 0, 0, 0);
            }

            // Partials: C/D layout col=lane&15, row=(lane>>4)*4+r
#pragma unroll
            for (int n2 = 0; n2 < 2; ++n2) {
                const int bb = (lane >> 4) << 2;
#pragma unroll
                for (int r = 0; r < 4; ++r)
                    gl[w][bb + r][(n2 << 4) + rA] = acc[n2][r];
            }
            __syncthreads();

            // Gates: thread (gb, gc); gate-row index = gt*8 + gc
            if (tid < 128) {
                float gv[4];
#pragma unroll
                for (int gt = 0; gt < 4; ++gt)
                    gv[gt] = gl[0][gb][(gt << 3) + gc] + gl[1][gb][(gt << 3) + gc]
                           + gl[2][gb][(gt << 3) + gc] + gl[3][gb][(gt << 3) + gc]
                           + brg[gt] + xv[gt];
                const float i_ = fast_sigmoid(gv[0]);
                const float f_ = fast_sigmoid(gv[1]);
                const float o_ = fast_sigmoid(gv[2]);
                const float ct = fast_tanh(gv[3]);
                const float cn = f_ * creg[g] + i_ * ct;
                creg[g] = cn;
                if (tid < 128) hs[gb][gc] = o_ * fast_tanh(cn);
            }
            __syncthreads();

            // Stores: one batch row per thread (tid<16): 32B out + 16B h (agent).
            if (tid < 16) {
                float v[8];
#pragma unroll
                for (int k = 0; k < 8; ++k) v[k] = hs[tid][k];
                float* orow = out + (((size_t)s << 6) + (g << 4) + tid) * 1024 + j0;
                *reinterpret_cast<float4*>(orow)     = make_float4(v[0], v[1], v[2], v[3]);
                *reinterpret_cast<float4*>(orow + 4) = make_float4(v[4], v[5], v[6], v[7]);
                union { __hip_bfloat16 bh[8]; u64 q[2]; } u;
#pragma unroll
                for (int k = 0; k < 8; ++k) u.bh[k] = __float2bfloat16(v[k]);
                u64* hq = (u64*)(hbuf + (((size_t)((slw << 2) + g)) << 14) + (tid << 10) + j0);
                __hip_atomic_store(hq,     u.q[0], __ATOMIC_RELAXED, __HIP_MEMORY_SCOPE_AGENT);
                __hip_atomic_store(hq + 1, u.q[1], __ATOMIC_RELAXED, __HIP_MEMORY_SCOPE_AGENT);
            }
            // flag for this chain is posted next phase (after its sync drains acks)
        }
    }

    // Final drain + post chain 3's last flag (chains 0-2 posted in final iter).
    __syncthreads();
    if (tid == 0)
        __hip_atomic_store(flags + 3 * fstride + (int)blockIdx.x * 16,
                           stepBase + (unsigned)TC,
                           __ATOMIC_RELAXED, __HIP_MEMORY_SCOPE_AGENT);

    // Persist c for next chunk / epilogue
    if (tid < 128) {
#pragma unroll
        for (int g = 0; g < NCHAIN; ++g)
            cbuf[(((g << 4) + gb) << 10) + j0 + gc] = creg[g];
    }
}

extern "C" void kernel_launch(void* const* d_in, const int* in_sizes, int n_in,
                              void* d_out, int out_size, void* d_ws, size_t ws_size,
                              hipStream_t stream)
{
    const float* inputs = (const float*)d_in[0];
    const float* H0     = (const float*)d_in[1];
    const float* C0     = (const float*)d_in[2];

    WP wp;
    wp.wx[0] = (const float*)d_in[3];  wp.bx[0] = (const float*)d_in[4];
    wp.wh[0] = (const float*)d_in[5];  wp.bh[0] = (const float*)d_in[6];
    wp.wx[1] = (const float*)d_in[7];  wp.bx[1] = (const float*)d_in[8];
    wp.wh[1] = (const float*)d_in[9];  wp.bh[1] = (const float*)d_in[10];
    wp.wx[2] = (const float*)d_in[11]; wp.bx[2] = (const float*)d_in[12];
    wp.wh[2] = (const float*)d_in[13]; wp.bh[2] = (const float*)d_in[14];
    wp.wx[3] = (const float*)d_in[15]; wp.bx[3] = (const float*)d_in[16];
    wp.wh[3] = (const float*)d_in[17]; wp.bh[3] = (const float*)d_in[18];

    char* ws = (char*)d_ws;
    size_t off = 0;
    auto alloc = [&](size_t bytes) {
        void* p = ws + off;
        off = (off + bytes + 255) & ~(size_t)255;
        return p;
    };
    __hip_bfloat16* Wx   = (__hip_bfloat16*)alloc((size_t)4 * HDIM * INDIM * 2);
    __hip_bfloat16* Wh   = (__hip_bfloat16*)alloc((size_t)4 * HDIM * HDIM * 2);
    float*          bias = (float*)alloc((size_t)4 * HDIM * 4);
    __hip_bfloat16* xb   = (__hip_bfloat16*)alloc((size_t)T_STEPS * BATCH * INDIM * 2);
    __hip_bfloat16* hbuf = (__hip_bfloat16*)alloc((size_t)2 * NCHAIN * 16 * HDIM * 2);
    float*          cbuf = (float*)alloc((size_t)BATCH * HDIM * 4);
    unsigned*       flags= (unsigned*)alloc((size_t)NCHAIN * NWG * 16 * 4);

    const size_t per_t = (size_t)4 * HDIM * BATCH * 4;
    int TC = 0;
    for (int tc : {512, 256, 128, 64, 32, 16})
        if (off + (size_t)tc * per_t <= ws_size) { TC = tc; break; }
    if (TC == 0) return;
    float* xp = (float*)alloc((size_t)TC * per_t);

    float* out = (float*)d_out;

    hipMemsetAsync(flags, 0, (size_t)NCHAIN * NWG * 16 * 4, stream);  // deterministic
    hipLaunchKernelGGL(pack_weights, dim3(2048), dim3(256), 0, stream, wp, Wx, Wh, bias);
    hipLaunchKernelGGL(cast_f32_bf16, dim3(2048), dim3(256), 0, stream,
                       inputs, xb, T_STEPS * BATCH * INDIM / 4);
    hipLaunchKernelGGL(init_state, dim3(256), dim3(256), 0, stream, H0, C0, hbuf, cbuf);

    unsigned stepBase = 0;
    for (int t0 = 0; t0 < T_STEPS; t0 += TC) {
        hipLaunchKernelGGL(xproj_gemm, dim3(TC, 32), dim3(256), 0, stream,
                           xb + (size_t)t0 * BATCH * INDIM, Wx, xp);
        hipLaunchKernelGGL(lstm_persist, dim3(NWG), dim3(256), 0, stream,
                           (const float*)xp, (const __hip_bfloat16*)Wh,
                           (const float*)bias, hbuf, cbuf,
                           out + (size_t)t0 * BATCH * HDIM, flags, stepBase, TC);
        stepBase += (unsigned)TC;
    }
    hipLaunchKernelGGL(epilogue, dim3(256), dim3(256), 0, stream,
                       out + (size_t)(T_STEPS - 1) * BATCH * HDIM, cbuf,
                       out + (size_t)T_STEPS * BATCH * HDIM,
                       out + (size_t)T_STEPS * BATCH * HDIM + BATCH * HDIM);
}

// Round 8
// 7005.273 us; speedup vs baseline: 1.2162x; 1.2162x over previous
//
#include <hip/hip_runtime.h>
#include <hip/hip_bf16.h>
#include <math.h>

#define T_STEPS 512
#define BATCH   64
#define INDIM   1024
#define HDIM    1024
#define NWG     128      // persistent compute WGs; each owns 8 hidden cols

using bf16x8 = __attribute__((ext_vector_type(8))) __bf16;
using f32x4  = __attribute__((ext_vector_type(4))) float;
typedef unsigned long long u64;

struct WP {
    const float* wx[4];
    const float* wh[4];
    const float* bx[4];
    const float* bh[4];
};

// Pack 8 weight matrices into combined bf16 [4H][K] layouts + combined bias.
__global__ void pack_weights(WP p, __hip_bfloat16* __restrict__ Wx,
                             __hip_bfloat16* __restrict__ Wh, float* __restrict__ bias)
{
    int i = blockIdx.x * blockDim.x + threadIdx.x;
    const int stride = gridDim.x * blockDim.x;
    const int total = 4 * HDIM * INDIM;
    for (int idx = i; idx < total; idx += stride) {
        int g = idx >> 20;
        int r = idx & ((1 << 20) - 1);
        Wx[idx] = __float2bfloat16(p.wx[g][r]);
        Wh[idx] = __float2bfloat16(p.wh[g][r]);
    }
    if (i < 4 * HDIM) {
        int g = i >> 10, r = i & 1023;
        bias[i] = p.bx[g][r] + p.bh[g][r];
    }
}

__global__ void cast_f32_bf16(const float* __restrict__ in,
                              __hip_bfloat16* __restrict__ out, int n4)
{
    int i = blockIdx.x * blockDim.x + threadIdx.x;
    const int stride = gridDim.x * blockDim.x;
    for (; i < n4; i += stride) {
        float4 v = ((const float4*)in)[i];
        union { __hip_bfloat16 b[4]; short4 s; } u;
        u.b[0] = __float2bfloat16(v.x);
        u.b[1] = __float2bfloat16(v.y);
        u.b[2] = __float2bfloat16(v.z);
        u.b[3] = __float2bfloat16(v.w);
        ((short4*)out)[i] = u.s;
    }
}

__global__ void init_state(const float* __restrict__ H0, const float* __restrict__ C0,
                           __hip_bfloat16* __restrict__ h0, float* __restrict__ c)
{
    int i = blockIdx.x * blockDim.x + threadIdx.x;
    if (i < BATCH * HDIM) {
        h0[i] = __float2bfloat16(H0[i]);
        c[i]  = C0[i];
    }
}

__global__ void epilogue(const float* __restrict__ lasth, const float* __restrict__ c,
                         float* __restrict__ Hf, float* __restrict__ Cf)
{
    int i = blockIdx.x * blockDim.x + threadIdx.x;
    if (i < BATCH * HDIM) {
        Hf[i] = lasth[i];
        Cf[i] = c[i];
    }
}

// xproj GEMM: xp[t][n][b] = sum_k xb[t*64+b][k] * Wx[n][k]   (f32 out)
__global__ __launch_bounds__(256, 2) void xproj_gemm(
    const __hip_bfloat16* __restrict__ xb,   // chunk base [TC*64][1024]
    const __hip_bfloat16* __restrict__ Wx,   // [4096][1024]
    float* __restrict__ xp)                  // [TC][4096][64]
{
    __shared__ float ct[4][64][33];
    const int t = blockIdx.x;
    const int n0 = blockIdx.y << 7;
    const int tid = threadIdx.x, w = tid >> 6, lane = tid & 63;
    const int rA = lane & 15, kg = (lane >> 4) << 3;
    const int nw = n0 + (w << 5);
    f32x4 acc[2][4] = {};
    const __hip_bfloat16* Arow = xb + (((size_t)t << 6) + rA) * 1024 + kg;
    const __hip_bfloat16* Brow = Wx + ((size_t)(nw + rA) << 10) + kg;
#pragma unroll 4
    for (int kk = 0; kk < 32; ++kk) {
        const int kb = kk << 5;
        bf16x8 bf0 = *reinterpret_cast<const bf16x8*>(Brow + kb);
        bf16x8 bf1 = *reinterpret_cast<const bf16x8*>(Brow + (16 << 10) + kb);
        bf16x8 af[4];
#pragma unroll
        for (int m = 0; m < 4; ++m)
            af[m] = *reinterpret_cast<const bf16x8*>(Arow + (m << 14) + kb);
#pragma unroll
        for (int m = 0; m < 4; ++m) {
            acc[0][m] = __builtin_amdgcn_mfma_f32_16x16x32_bf16(af[m], bf0, acc[0][m], 0, 0, 0);
            acc[1][m] = __builtin_amdgcn_mfma_f32_16x16x32_bf16(af[m], bf1, acc[1][m], 0, 0, 0);
        }
    }
#pragma unroll
    for (int n2 = 0; n2 < 2; ++n2)
#pragma unroll
        for (int m = 0; m < 4; ++m) {
            const int bb = (m << 4) + ((lane >> 4) << 2);
#pragma unroll
            for (int r = 0; r < 4; ++r)
                ct[w][bb + r][(n2 << 4) + rA] = acc[n2][m][r];
        }
    __syncthreads();
    const int n = lane & 31, mh = lane >> 5;
    float* obase = xp + ((size_t)t * 4096 + nw + n) * 64 + (mh << 5);
#pragma unroll
    for (int j = 0; j < 8; ++j) {
        const int m0 = (mh << 5) + (j << 2);
        *reinterpret_cast<float4*>(obase + (j << 2)) = make_float4(
            ct[w][m0 + 0][n], ct[w][m0 + 1][n], ct[w][m0 + 2][n], ct[w][m0 + 3][n]);
    }
}

__device__ __forceinline__ float fast_sigmoid(float x)
{
    return 1.f / (1.f + __expf(-x));
}
__device__ __forceinline__ float fast_tanh(float x)
{
    x = fminf(15.f, fmaxf(-15.f, x));
    const float e = __expf(2.f * x);
    return (e - 1.f) / (e + 1.f);
}

// Persistent recurrence. Grid = NWG+1 blocks x 256 threads.
// Block NWG = dedicated aggregator: sweeps the 128 per-WG flags with one
// wave (2 flags/lane, __all reduce) and publishes a single epoch counter.
// Compute WGs poll ONLY the epoch with one thread (sleep between polls):
// total poll traffic at the MALL drops ~64x vs R6 (the R3-R7 bottleneck).
// All cross-WG data via relaxed agent-scope atomics (MALL-coherent, no
// L2 fences). Visibility chain: h-stores (atomic) drained by syncthreads
// -> flag (relaxed) -> aggregator reads flags -> epoch -> pollee reads
// epoch -> h atomic loads see MALL-resident data. Bounded spins: a logic
// bug yields wrong output (visible failure), not a wedged container.
__global__ __launch_bounds__(256, 1) void lstm_persist(
    const float* __restrict__ xp,            // [TC][4096][64]
    const __hip_bfloat16* __restrict__ Wh,   // [4096][1024]
    const float* __restrict__ bias,          // [4096]
    __hip_bfloat16* __restrict__ hA,         // state at chunk start
    __hip_bfloat16* __restrict__ hB,
    float* __restrict__ cbuf,                // [64][1024]
    float* __restrict__ out,                 // [TC][64][1024]
    unsigned* __restrict__ flags,            // [NWG*16] + epoch at [NWG*16]
    unsigned stepBase,
    int TC)
{
    const int tid  = threadIdx.x;
    unsigned* epoch = flags + NWG * 16;

    // ---- Aggregator block: no compute, wave 0 only. ----
    if (blockIdx.x == NWG) {
        if (tid < 64) {
            const unsigned* f0 = flags + tid * 16;
            const unsigned* f1 = flags + (tid + 64) * 16;
            for (int s = 0; s < TC; ++s) {
                const unsigned tgt = stepBase + (unsigned)(s + 1);
                int guard = 1 << 22;
                for (;;) {
                    int ok = (__hip_atomic_load(f0, __ATOMIC_RELAXED, __HIP_MEMORY_SCOPE_AGENT) >= tgt) &&
                             (__hip_atomic_load(f1, __ATOMIC_RELAXED, __HIP_MEMORY_SCOPE_AGENT) >= tgt);
                    if (__all(ok) || --guard <= 0) break;
                    __builtin_amdgcn_s_sleep(1);
                }
                if (tid == 0)
                    __hip_atomic_store(epoch, tgt, __ATOMIC_RELAXED, __HIP_MEMORY_SCOPE_AGENT);
            }
        }
        return;
    }

    __shared__ float gl[4][64][33];          // per-wave partials [w][b][r<32]
    __shared__ float hs[64][9];              // gathered h f32 (for out stores)

    const int w    = tid >> 6;
    const int lane = tid & 63;
    const int rA   = lane & 15;
    const int kg   = (lane >> 4) << 3;
    const int j0   = blockIdx.x << 3;

    // Wave's Wh fragments: its K-quarter of the WG's 32 gate-rows.
    bf16x8 whf[2][8];
#pragma unroll
    for (int n2 = 0; n2 < 2; ++n2) {
        const int row  = (n2 << 4) + rA;
        const int grow = ((row >> 3) << 10) + j0 + (row & 7);
        const __hip_bfloat16* wr = Wh + ((size_t)grow << 10) + (w << 8) + kg;
#pragma unroll
        for (int kk = 0; kk < 8; ++kk)
            whf[n2][kk] = *reinterpret_cast<const bf16x8*>(wr + (kk << 5));
    }

    // Gate-phase persistent state: thread (b=lane, cols cl=w*2+{0,1})
    const int b = lane;
    float creg[2], brg[2][4];
#pragma unroll
    for (int e = 0; e < 2; ++e) {
        const int cl = (w << 1) + e;
        creg[e] = cbuf[(b << 10) + j0 + cl];
#pragma unroll
        for (int g = 0; g < 4; ++g) brg[e][g] = bias[(g << 10) + j0 + cl];
    }

#define LOAD_XV(dst, sidx)                                                     \
    do {                                                                       \
        const float* xpt_ = xp + (size_t)(sidx) * 262144;                      \
        _Pragma("unroll") for (int e = 0; e < 2; ++e)                          \
        _Pragma("unroll") for (int g = 0; g < 4; ++g)                          \
            dst[e][g] = xpt_[(((g << 10) + j0 + (w << 1) + e) << 6) + b];      \
    } while (0)

    float xv[2][4];
    LOAD_XV(xv, 0);

    for (int s = 0; s < TC; ++s) {
        const __hip_bfloat16* hp = (s & 1) ? hB : hA;
        __hip_bfloat16*       hn = (s & 1) ? hA : hB;
        const unsigned tgt = stepBase + (unsigned)(s + 1);

        // Prefetch next step's xproj (latency hides under GEMM+wait).
        float xn[2][4];
        if (s + 1 < TC) LOAD_XV(xn, s + 1);

        // h-GEMM: this wave's K-quarter. h via relaxed agent u64 atomics.
        f32x4 acc[2][4] = {};
        const __hip_bfloat16* hbase = hp + (w << 8) + kg;
#pragma unroll
        for (int hhalf = 0; hhalf < 2; ++hhalf) {
            u64 aq[4][4][2];
#pragma unroll
            for (int k2 = 0; k2 < 4; ++k2) {
                const int kk = (hhalf << 2) + k2;
#pragma unroll
                for (int m = 0; m < 4; ++m) {
                    const u64* p = (const u64*)(hbase + (((m << 4) + rA) << 10) + (kk << 5));
                    aq[k2][m][0] = __hip_atomic_load(p,     __ATOMIC_RELAXED, __HIP_MEMORY_SCOPE_AGENT);
                    aq[k2][m][1] = __hip_atomic_load(p + 1, __ATOMIC_RELAXED, __HIP_MEMORY_SCOPE_AGENT);
                }
            }
#pragma unroll
            for (int k2 = 0; k2 < 4; ++k2) {
                const int kk = (hhalf << 2) + k2;
#pragma unroll
                for (int m = 0; m < 4; ++m) {
                    union { u64 q[2]; bf16x8 v; } c;
                    c.q[0] = aq[k2][m][0];
                    c.q[1] = aq[k2][m][1];
#pragma unroll
                    for (int n2 = 0; n2 < 2; ++n2)
                        acc[n2][m] = __builtin_amdgcn_mfma_f32_16x16x32_bf16(
                            c.v, whf[n2][kk], acc[n2][m], 0, 0, 0);
                }
            }
        }

        // Partials: C/D layout col=lane&15, row=(lane>>4)*4+r
#pragma unroll
        for (int n2 = 0; n2 < 2; ++n2)
#pragma unroll
            for (int m = 0; m < 4; ++m) {
                const int bb = (m << 4) + ((lane >> 4) << 2);
#pragma unroll
                for (int r = 0; r < 4; ++r)
                    gl[w][bb + r][(n2 << 4) + rA] = acc[n2][m][r];
            }
        __syncthreads();

        // Gates: thread (b, cl=w*2+e). h stored DIRECTLY as packed u32
        // atomic (both cols of this thread are adjacent) - no LDS detour.
        {
            float hv[2];
#pragma unroll
            for (int e = 0; e < 2; ++e) {
                const int cl = (w << 1) + e;
                float gv[4];
#pragma unroll
                for (int g = 0; g < 4; ++g)
                    gv[g] = gl[0][b][(g << 3) + cl] + gl[1][b][(g << 3) + cl]
                          + gl[2][b][(g << 3) + cl] + gl[3][b][(g << 3) + cl]
                          + brg[e][g] + xv[e][g];
                const float i_ = fast_sigmoid(gv[0]);
                const float f_ = fast_sigmoid(gv[1]);
                const float o_ = fast_sigmoid(gv[2]);
                const float ct = fast_tanh(gv[3]);
                const float cn = f_ * creg[e] + i_ * ct;
                creg[e] = cn;
                hv[e] = o_ * fast_tanh(cn);
                hs[b][cl] = hv[e];
            }
            union { __hip_bfloat16 bh[2]; unsigned u; } pk;
            pk.bh[0] = __float2bfloat16(hv[0]);
            pk.bh[1] = __float2bfloat16(hv[1]);
            unsigned* hq = (unsigned*)(hn + ((size_t)b << 10) + j0 + (w << 1));
            __hip_atomic_store(hq, pk.u, __ATOMIC_RELAXED, __HIP_MEMORY_SCOPE_AGENT);
        }
        __syncthreads();                     // drains all h-stores (vmcnt 0)

        // Publish this WG's flag; out-stores AFTER it (ack overlaps wait).
        if (tid == 0)
            __hip_atomic_store(&flags[(int)blockIdx.x * 16], tgt,
                               __ATOMIC_RELAXED, __HIP_MEMORY_SCOPE_AGENT);
        if (tid < 64) {
            float v[8];
#pragma unroll
            for (int k = 0; k < 8; ++k) v[k] = hs[tid][k];
            float* orow = out + (((size_t)s << 6) + tid) * 1024 + j0;
            *reinterpret_cast<float4*>(orow)     = make_float4(v[0], v[1], v[2], v[3]);
            *reinterpret_cast<float4*>(orow + 4) = make_float4(v[4], v[5], v[6], v[7]);
        }

        // Epoch wait: one thread polls, gentle sleep.
        if (tid == 0) {
            int guard = 1 << 22;
            while (__hip_atomic_load(epoch, __ATOMIC_RELAXED, __HIP_MEMORY_SCOPE_AGENT) < tgt
                   && --guard > 0)
                __builtin_amdgcn_s_sleep(4);
        }
        __syncthreads();

#pragma unroll
        for (int e = 0; e < 2; ++e)
#pragma unroll
            for (int g = 0; g < 4; ++g)
                xv[e][g] = xn[e][g];
    }

    // Persist c for next chunk / epilogue.
#pragma unroll
    for (int e = 0; e < 2; ++e)
        cbuf[(b << 10) + j0 + (w << 1) + e] = creg[e];
}

extern "C" void kernel_launch(void* const* d_in, const int* in_sizes, int n_in,
                              void* d_out, int out_size, void* d_ws, size_t ws_size,
                              hipStream_t stream)
{
    const float* inputs = (const float*)d_in[0];
    const float* H0     = (const float*)d_in[1];
    const float* C0     = (const float*)d_in[2];

    WP wp;
    wp.wx[0] = (const float*)d_in[3];  wp.bx[0] = (const float*)d_in[4];
    wp.wh[0] = (const float*)d_in[5];  wp.bh[0] = (const float*)d_in[6];
    wp.wx[1] = (const float*)d_in[7];  wp.bx[1] = (const float*)d_in[8];
    wp.wh[1] = (const float*)d_in[9];  wp.bh[1] = (const float*)d_in[10];
    wp.wx[2] = (const float*)d_in[11]; wp.bx[2] = (const float*)d_in[12];
    wp.wh[2] = (const float*)d_in[13]; wp.bh[2] = (const float*)d_in[14];
    wp.wx[3] = (const float*)d_in[15]; wp.bx[3] = (const float*)d_in[16];
    wp.wh[3] = (const float*)d_in[17]; wp.bh[3] = (const float*)d_in[18];

    char* ws = (char*)d_ws;
    size_t off = 0;
    auto alloc = [&](size_t bytes) {
        void* p = ws + off;
        off = (off + bytes + 255) & ~(size_t)255;
        return p;
    };
    __hip_bfloat16* Wx   = (__hip_bfloat16*)alloc((size_t)4 * HDIM * INDIM * 2);
    __hip_bfloat16* Wh   = (__hip_bfloat16*)alloc((size_t)4 * HDIM * HDIM * 2);
    float*          bias = (float*)alloc((size_t)4 * HDIM * 4);
    __hip_bfloat16* xb   = (__hip_bfloat16*)alloc((size_t)T_STEPS * BATCH * INDIM * 2);
    __hip_bfloat16* hb0  = (__hip_bfloat16*)alloc((size_t)BATCH * HDIM * 2);
    __hip_bfloat16* hb1  = (__hip_bfloat16*)alloc((size_t)BATCH * HDIM * 2);
    float*          cbuf = (float*)alloc((size_t)BATCH * HDIM * 4);
    unsigned*       flags= (unsigned*)alloc((size_t)(NWG + 1) * 16 * 4);

    const size_t per_t = (size_t)4 * HDIM * BATCH * 4;
    int TC = 0;
    for (int tc : {512, 256, 128, 64, 32, 16})
        if (off + (size_t)tc * per_t <= ws_size) { TC = tc; break; }
    if (TC == 0) return;
    float* xp = (float*)alloc((size_t)TC * per_t);

    float* out = (float*)d_out;

    hipMemsetAsync(flags, 0, (size_t)(NWG + 1) * 16 * 4, stream);  // deterministic
    hipLaunchKernelGGL(pack_weights, dim3(2048), dim3(256), 0, stream, wp, Wx, Wh, bias);
    hipLaunchKernelGGL(cast_f32_bf16, dim3(2048), dim3(256), 0, stream,
                       inputs, xb, T_STEPS * BATCH * INDIM / 4);
    hipLaunchKernelGGL(init_state, dim3(256), dim3(256), 0, stream, H0, C0, hb0, cbuf);

    unsigned stepBase = 0;
    for (int t0 = 0; t0 < T_STEPS; t0 += TC) {
        hipLaunchKernelGGL(xproj_gemm, dim3(TC, 32), dim3(256), 0, stream,
                           xb + (size_t)t0 * BATCH * INDIM, Wx, xp);
        hipLaunchKernelGGL(lstm_persist, dim3(NWG + 1), dim3(256), 0, stream,
                           (const float*)xp, (const __hip_bfloat16*)Wh,
                           (const float*)bias, hb0, hb1, cbuf,
                           out + (size_t)t0 * BATCH * HDIM, flags, stepBase, TC);
        stepBase += (unsigned)TC;
    }
    hipLaunchKernelGGL(epilogue, dim3(256), dim3(256), 0, stream,
                       out + (size_t)(T_STEPS - 1) * BATCH * HDIM, cbuf,
                       out + (size_t)T_STEPS * BATCH * HDIM,
                       out + (size_t)T_STEPS * BATCH * HDIM + BATCH * HDIM);
}

// Round 10
// 4849.136 us; speedup vs baseline: 1.7570x; 1.4446x over previous
//
#include <hip/hip_runtime.h>
#include <hip/hip_bf16.h>
#include <math.h>

#define T_STEPS 512
#define BATCH   64
#define INDIM   1024
#define HDIM    1024
#define NWG     128      // persistent compute WGs; each owns 8 hidden cols

using bf16x8 = __attribute__((ext_vector_type(8))) __bf16;
using f32x4  = __attribute__((ext_vector_type(4))) float;
typedef unsigned long long u64;

struct WP {
    const float* wx[4];
    const float* wh[4];
    const float* bx[4];
    const float* bh[4];
};

// Pack 8 weight matrices into combined bf16 [4H][K] layouts + combined bias.
__global__ void pack_weights(WP p, __hip_bfloat16* __restrict__ Wx,
                             __hip_bfloat16* __restrict__ Wh, float* __restrict__ bias)
{
    int i = blockIdx.x * blockDim.x + threadIdx.x;
    const int stride = gridDim.x * blockDim.x;
    const int total = 4 * HDIM * INDIM;
    for (int idx = i; idx < total; idx += stride) {
        int g = idx >> 20;
        int r = idx & ((1 << 20) - 1);
        Wx[idx] = __float2bfloat16(p.wx[g][r]);
        Wh[idx] = __float2bfloat16(p.wh[g][r]);
    }
    if (i < 4 * HDIM) {
        int g = i >> 10, r = i & 1023;
        bias[i] = p.bx[g][r] + p.bh[g][r];
    }
}

__global__ void cast_f32_bf16(const float* __restrict__ in,
                              __hip_bfloat16* __restrict__ out, int n4)
{
    int i = blockIdx.x * blockDim.x + threadIdx.x;
    const int stride = gridDim.x * blockDim.x;
    for (; i < n4; i += stride) {
        float4 v = ((const float4*)in)[i];
        union { __hip_bfloat16 b[4]; short4 s; } u;
        u.b[0] = __float2bfloat16(v.x);
        u.b[1] = __float2bfloat16(v.y);
        u.b[2] = __float2bfloat16(v.z);
        u.b[3] = __float2bfloat16(v.w);
        ((short4*)out)[i] = u.s;
    }
}

// h exchange buffer: MFMA-fragment-packed layout.
// hx[slot][ ((w*8+kk)*4+m) ][lane][8 bf16] :
//   element (block(w,kk,m), lane l, i) = h[16m + (l&15)][256w + 32kk + 8*(l>>4) + i]
// Consumer lane l reads 16B at +l*16B (1KB contiguous per block).
// Producer WG bw (cols 8bw..8bw+7) = triple (w=bw>>5, kk=(bw>>2)&7, lhi=bw&3):
// each row r is one 16B store at lane (lhi*16 + (r&15)), block m=r>>4.
__global__ void init_state(const float* __restrict__ H0, const float* __restrict__ C0,
                           __hip_bfloat16* __restrict__ hx, float* __restrict__ c)
{
    int i = blockIdx.x * blockDim.x + threadIdx.x;
    if (i < BATCH * HDIM) {
        int b = i >> 10, j = i & 1023;
        int m = b >> 4, rA = b & 15;
        int wv = j >> 8, kk = (j >> 5) & 7, lhi = (j >> 3) & 3, ii = j & 7;
        size_t idx = ((((size_t)(wv << 3) + kk) << 2) + m) * 512
                   + (((lhi << 4) + rA) << 3) + ii;
        hx[idx] = __float2bfloat16(H0[i]);
        c[i] = C0[i];
    }
}

__global__ void epilogue(const float* __restrict__ lasth, const float* __restrict__ c,
                         float* __restrict__ Hf, float* __restrict__ Cf)
{
    int i = blockIdx.x * blockDim.x + threadIdx.x;
    if (i < BATCH * HDIM) {
        Hf[i] = lasth[i];
        Cf[i] = c[i];
    }
}

// xproj GEMM: xp[t][n][b] = sum_k xb[t*64+b][k] * Wx[n][k]   (f32 out)
__global__ __launch_bounds__(256, 2) void xproj_gemm(
    const __hip_bfloat16* __restrict__ xb,   // chunk base [TC*64][1024]
    const __hip_bfloat16* __restrict__ Wx,   // [4096][1024]
    float* __restrict__ xp)                  // [TC][4096][64]
{
    __shared__ float ct[4][64][33];
    const int t = blockIdx.x;
    const int n0 = blockIdx.y << 7;
    const int tid = threadIdx.x, w = tid >> 6, lane = tid & 63;
    const int rA = lane & 15, kg = (lane >> 4) << 3;
    const int nw = n0 + (w << 5);
    f32x4 acc[2][4] = {};
    const __hip_bfloat16* Arow = xb + (((size_t)t << 6) + rA) * 1024 + kg;
    const __hip_bfloat16* Brow = Wx + ((size_t)(nw + rA) << 10) + kg;
#pragma unroll 4
    for (int kk = 0; kk < 32; ++kk) {
        const int kb = kk << 5;
        bf16x8 bf0 = *reinterpret_cast<const bf16x8*>(Brow + kb);
        bf16x8 bf1 = *reinterpret_cast<const bf16x8*>(Brow + (16 << 10) + kb);
        bf16x8 af[4];
#pragma unroll
        for (int m = 0; m < 4; ++m)
            af[m] = *reinterpret_cast<const bf16x8*>(Arow + (m << 14) + kb);
#pragma unroll
        for (int m = 0; m < 4; ++m) {
            acc[0][m] = __builtin_amdgcn_mfma_f32_16x16x32_bf16(af[m], bf0, acc[0][m], 0, 0, 0);
            acc[1][m] = __builtin_amdgcn_mfma_f32_16x16x32_bf16(af[m], bf1, acc[1][m], 0, 0, 0);
        }
    }
#pragma unroll
    for (int n2 = 0; n2 < 2; ++n2)
#pragma unroll
        for (int m = 0; m < 4; ++m) {
            const int bb = (m << 4) + ((lane >> 4) << 2);
#pragma unroll
            for (int r = 0; r < 4; ++r)
                ct[w][bb + r][(n2 << 4) + rA] = acc[n2][m][r];
        }
    __syncthreads();
    const int n = lane & 31, mh = lane >> 5;
    float* obase = xp + ((size_t)t * 4096 + nw + n) * 64 + (mh << 5);
#pragma unroll
    for (int j = 0; j < 8; ++j) {
        const int m0 = (mh << 5) + (j << 2);
        *reinterpret_cast<float4*>(obase + (j << 2)) = make_float4(
            ct[w][m0 + 0][n], ct[w][m0 + 1][n], ct[w][m0 + 2][n], ct[w][m0 + 3][n]);
    }
}

// Fence-free distributed-flag barrier (R6-proven). Guard shortened so a
// pathological stall exits in ~ms (visible bench failure, not a wedged
// container): 2^18 polls x ~sleep(2) ~= few ms per barrier worst case.
__device__ __forceinline__ void gbar_nofence(unsigned* flags, unsigned target)
{
    __syncthreads();                         // vmcnt(0): h atomics acked at MALL
    if (threadIdx.x == 0)
        __hip_atomic_store(&flags[(int)blockIdx.x * 16], target,
                           __ATOMIC_RELAXED, __HIP_MEMORY_SCOPE_AGENT);
    if (threadIdx.x < 64) {
        const unsigned* f0 = &flags[threadIdx.x * 16];
        const unsigned* f1 = &flags[(threadIdx.x + 64) * 16];
        int guard = 1 << 18;
        while ((__hip_atomic_load(f0, __ATOMIC_RELAXED, __HIP_MEMORY_SCOPE_AGENT) < target ||
                __hip_atomic_load(f1, __ATOMIC_RELAXED, __HIP_MEMORY_SCOPE_AGENT) < target)
               && --guard > 0)
            __builtin_amdgcn_s_sleep(2);
    }
    __syncthreads();
}

__device__ __forceinline__ float fast_sigmoid(float x)
{
    return 1.f / (1.f + __expf(-x));
}
__device__ __forceinline__ float fast_tanh(float x)
{
    x = fminf(15.f, fmaxf(-15.f, x));
    const float e = __expf(2.f * x);
    return (e - 1.f) / (e + 1.f);
}

// Persistent recurrence. Grid = NWG(128) x 256 threads.
// Identical to R6 except the h exchange uses the fragment-packed hx layout:
// consumer atomic loads and producer atomic stores are fully coalesced
// (consecutive lanes -> consecutive addresses), cutting MALL line-requests
// ~8x (the R6/R8 residual bottleneck hypothesis).
__global__ __launch_bounds__(256, 1) void lstm_persist(
    const float* __restrict__ xp,            // [TC][4096][64]
    const __hip_bfloat16* __restrict__ Wh,   // [4096][1024]
    const float* __restrict__ bias,          // [4096]
    u64* __restrict__ hxA,                   // packed h slot A (state at chunk start)
    u64* __restrict__ hxB,                   // packed h slot B
    float* __restrict__ cbuf,                // [64][1024]
    float* __restrict__ out,                 // [TC][64][1024]
    unsigned* __restrict__ flags,            // [NWG*16]
    unsigned stepBase,
    int TC)
{
    __shared__ float gl[4][64][33];          // per-wave partials [w][b][r<32]
    __shared__ float hs[64][9];              // gathered h f32

    const int tid  = threadIdx.x;
    const int w    = tid >> 6;
    const int lane = tid & 63;
    const int rA   = lane & 15;
    const int j0   = blockIdx.x << 3;

    // Wave's Wh fragments: its K-quarter of the WG's 32 gate-rows.
    const int kg = (lane >> 4) << 3;
    bf16x8 whf[2][8];
#pragma unroll
    for (int n2 = 0; n2 < 2; ++n2) {
        const int row  = (n2 << 4) + rA;
        const int grow = ((row >> 3) << 10) + j0 + (row & 7);
        const __hip_bfloat16* wr = Wh + ((size_t)grow << 10) + (w << 8) + kg;
#pragma unroll
        for (int kk = 0; kk < 8; ++kk)
            whf[n2][kk] = *reinterpret_cast<const bf16x8*>(wr + (kk << 5));
    }

    // Gate-phase persistent state: thread (b=lane, cols cl=w*2+{0,1})
    const int b = lane;
    float creg[2], brg[2][4];
#pragma unroll
    for (int e = 0; e < 2; ++e) {
        const int cl = (w << 1) + e;
        creg[e] = cbuf[(b << 10) + j0 + cl];
#pragma unroll
        for (int g = 0; g < 4; ++g) brg[e][g] = bias[(g << 10) + j0 + cl];
    }

    // Producer store base (in u64 units): WG bw -> triple (wc,kkc,lhi).
    const int bw  = blockIdx.x;
    const int pblk = (((bw >> 5) << 3) + ((bw >> 2) & 7)) << 2;   // (wc*8+kkc)*4

#define LOAD_XV(dst, sidx)                                                     \
    do {                                                                       \
        const float* xpt_ = xp + (size_t)(sidx) * 262144;                      \
        _Pragma("unroll") for (int e = 0; e < 2; ++e)                          \
        _Pragma("unroll") for (int g = 0; g < 4; ++g)                          \
            dst[e][g] = xpt_[(((g << 10) + j0 + (w << 1) + e) << 6) + b];      \
    } while (0)

    float xv[2][4];
    LOAD_XV(xv, 0);

    for (int s = 0; s < TC; ++s) {
        const u64* hp = (s & 1) ? hxB : hxA;
        u64*       hn = (s & 1) ? hxA : hxB;

        // Prefetch next step's xproj (latency hides under GEMM+wait).
        float xn[2][4];
        if (s + 1 < TC) LOAD_XV(xn, s + 1);

        // h-GEMM: this wave's K-quarter. Packed-coalesced atomic u64 loads:
        // per (kk,m) the wave reads 1KB contiguous.
        f32x4 acc[2][4] = {};
#pragma unroll
        for (int hhalf = 0; hhalf < 2; ++hhalf) {
            u64 aq[4][4][2];
#pragma unroll
            for (int k2 = 0; k2 < 4; ++k2) {
                const int kk = (hhalf << 2) + k2;
#pragma unroll
                for (int m = 0; m < 4; ++m) {
                    const u64* p = hp + ((((size_t)(w << 3) + kk) << 2) + m) * 128
                                     + (lane << 1);
                    aq[k2][m][0] = __hip_atomic_load(p,     __ATOMIC_RELAXED, __HIP_MEMORY_SCOPE_AGENT);
                    aq[k2][m][1] = __hip_atomic_load(p + 1, __ATOMIC_RELAXED, __HIP_MEMORY_SCOPE_AGENT);
                }
            }
#pragma unroll
            for (int k2 = 0; k2 < 4; ++k2) {
                const int kk = (hhalf << 2) + k2;
#pragma unroll
                for (int m = 0; m < 4; ++m) {
                    union { u64 q[2]; bf16x8 v; } c;
                    c.q[0] = aq[k2][m][0];
                    c.q[1] = aq[k2][m][1];
#pragma unroll
                    for (int n2 = 0; n2 < 2; ++n2)
                        acc[n2][m] = __builtin_amdgcn_mfma_f32_16x16x32_bf16(
                            c.v, whf[n2][kk], acc[n2][m], 0, 0, 0);
                }
            }
        }

        // Partials: C/D layout col=lane&15, row=(lane>>4)*4+r
#pragma unroll
        for (int n2 = 0; n2 < 2; ++n2)
#pragma unroll
            for (int m = 0; m < 4; ++m) {
                const int bb = (m << 4) + ((lane >> 4) << 2);
#pragma unroll
                for (int r = 0; r < 4; ++r)
                    gl[w][bb + r][(n2 << 4) + rA] = acc[n2][m][r];
            }
        __syncthreads();

        // Gates: thread (b, cl=w*2+e); write h row fragments to LDS.
#pragma unroll
        for (int e = 0; e < 2; ++e) {
            const int cl = (w << 1) + e;
            float gv[4];
#pragma unroll
            for (int g = 0; g < 4; ++g)
                gv[g] = gl[0][b][(g << 3) + cl] + gl[1][b][(g << 3) + cl]
                      + gl[2][b][(g << 3) + cl] + gl[3][b][(g << 3) + cl]
                      + brg[e][g] + xv[e][g];
            const float i_ = fast_sigmoid(gv[0]);
            const float f_ = fast_sigmoid(gv[1]);
            const float o_ = fast_sigmoid(gv[2]);
            const float ct = fast_tanh(gv[3]);
            const float cn = f_ * creg[e] + i_ * ct;
            creg[e] = cn;
            hs[b][cl] = o_ * fast_tanh(cn);
        }
        __syncthreads();

        // Row stores (tid<64 = batch row): out f32 (plain) + packed h (atomic,
        // coalesced: 16 consecutive threads -> 256B contiguous).
        if (tid < 64) {
            float v[8];
#pragma unroll
            for (int k = 0; k < 8; ++k) v[k] = hs[tid][k];
            float* orow = out + (((size_t)s << 6) + tid) * 1024 + j0;
            *reinterpret_cast<float4*>(orow)     = make_float4(v[0], v[1], v[2], v[3]);
            *reinterpret_cast<float4*>(orow + 4) = make_float4(v[4], v[5], v[6], v[7]);
            union { __hip_bfloat16 bh[8]; u64 q[2]; } u;
#pragma unroll
            for (int k = 0; k < 8; ++k) u.bh[k] = __float2bfloat16(v[k]);
            u64* hq = hn + ((size_t)(pblk + (tid >> 4))) * 128
                         + ((((bw & 3) << 4) + (tid & 15)) << 1);
            __hip_atomic_store(hq,     u.q[0], __ATOMIC_RELAXED, __HIP_MEMORY_SCOPE_AGENT);
            __hip_atomic_store(hq + 1, u.q[1], __ATOMIC_RELAXED, __HIP_MEMORY_SCOPE_AGENT);
        }
        gbar_nofence(flags, stepBase + (unsigned)(s + 1));

#pragma unroll
        for (int e = 0; e < 2; ++e)
#pragma unroll
            for (int g = 0; g < 4; ++g)
                xv[e][g] = xn[e][g];
    }

    // Persist c for next chunk / epilogue.
#pragma unroll
    for (int e = 0; e < 2; ++e)
        cbuf[(b << 10) + j0 + (w << 1) + e] = creg[e];
}

extern "C" void kernel_launch(void* const* d_in, const int* in_sizes, int n_in,
                              void* d_out, int out_size, void* d_ws, size_t ws_size,
                              hipStream_t stream)
{
    const float* inputs = (const float*)d_in[0];
    const float* H0     = (const float*)d_in[1];
    const float* C0     = (const float*)d_in[2];

    WP wp;
    wp.wx[0] = (const float*)d_in[3];  wp.bx[0] = (const float*)d_in[4];
    wp.wh[0] = (const float*)d_in[5];  wp.bh[0] = (const float*)d_in[6];
    wp.wx[1] = (const float*)d_in[7];  wp.bx[1] = (const float*)d_in[8];
    wp.wh[1] = (const float*)d_in[9];  wp.bh[1] = (const float*)d_in[10];
    wp.wx[2] = (const float*)d_in[11]; wp.bx[2] = (const float*)d_in[12];
    wp.wh[2] = (const float*)d_in[13]; wp.bh[2] = (const float*)d_in[14];
    wp.wx[3] = (const float*)d_in[15]; wp.bx[3] = (const float*)d_in[16];
    wp.wh[3] = (const float*)d_in[17]; wp.bh[3] = (const float*)d_in[18];

    char* ws = (char*)d_ws;
    size_t off = 0;
    auto alloc = [&](size_t bytes) {
        void* p = ws + off;
        off = (off + bytes + 255) & ~(size_t)255;
        return p;
    };
    __hip_bfloat16* Wx   = (__hip_bfloat16*)alloc((size_t)4 * HDIM * INDIM * 2);
    __hip_bfloat16* Wh   = (__hip_bfloat16*)alloc((size_t)4 * HDIM * HDIM * 2);
    float*          bias = (float*)alloc((size_t)4 * HDIM * 4);
    __hip_bfloat16* xb   = (__hip_bfloat16*)alloc((size_t)T_STEPS * BATCH * INDIM * 2);
    u64*            hx   = (u64*)alloc((size_t)2 * 16384 * 8);   // packed h, 2 slots
    float*          cbuf = (float*)alloc((size_t)BATCH * HDIM * 4);
    unsigned*       flags= (unsigned*)alloc((size_t)NWG * 16 * 4);

    const size_t per_t = (size_t)4 * HDIM * BATCH * 4;
    int TC = 0;
    for (int tc : {512, 256, 128, 64, 32, 16})
        if (off + (size_t)tc * per_t <= ws_size) { TC = tc; break; }
    if (TC == 0) return;
    float* xp = (float*)alloc((size_t)TC * per_t);

    float* out = (float*)d_out;

    hipMemsetAsync(flags, 0, (size_t)NWG * 16 * 4, stream);  // deterministic replays
    hipLaunchKernelGGL(pack_weights, dim3(2048), dim3(256), 0, stream, wp, Wx, Wh, bias);
    hipLaunchKernelGGL(cast_f32_bf16, dim3(2048), dim3(256), 0, stream,
                       inputs, xb, T_STEPS * BATCH * INDIM / 4);
    hipLaunchKernelGGL(init_state, dim3(256), dim3(256), 0, stream,
                       H0, C0, (__hip_bfloat16*)hx, cbuf);

    unsigned stepBase = 0;
    for (int t0 = 0; t0 < T_STEPS; t0 += TC) {
        hipLaunchKernelGGL(xproj_gemm, dim3(TC, 32), dim3(256), 0, stream,
                           xb + (size_t)t0 * BATCH * INDIM, Wx, xp);
        hipLaunchKernelGGL(lstm_persist, dim3(NWG), dim3(256), 0, stream,
                           (const float*)xp, (const __hip_bfloat16*)Wh,
                           (const float*)bias, hx, hx + 16384, cbuf,
                           out + (size_t)t0 * BATCH * HDIM, flags, stepBase, TC);
        stepBase += (unsigned)TC;
    }
    hipLaunchKernelGGL(epilogue, dim3(256), dim3(256), 0, stream,
                       out + (size_t)(T_STEPS - 1) * BATCH * HDIM, cbuf,
                       out + (size_t)T_STEPS * BATCH * HDIM,
                       out + (size_t)T_STEPS * BATCH * HDIM + BATCH * HDIM);
}